// Round 4
// 25923.557 us; speedup vs baseline: 1.0022x; 1.0022x over previous
//
#include <hip/hip_runtime.h>

typedef unsigned int   uint32;
typedef unsigned short u16;
typedef unsigned long long u64;
typedef __bf16 bf16x8 __attribute__((ext_vector_type(8)));
typedef u16    ushort8 __attribute__((ext_vector_type(8)));
typedef float  f32x4  __attribute__((ext_vector_type(4)));

// ---------------------------------------------------------------------------
// Exact 3-way bf16 split (truncation): v == bf(a)+bf(b)+bf(c) EXACTLY for all
// normal fp32 (24 mantissa bits = 8+8+8; each subtraction is exact).
// ---------------------------------------------------------------------------
struct Split3 { u16 a, b, c; };
__device__ __forceinline__ Split3 split3(float v) {
  uint32 u  = __float_as_uint(v);
  u16 s1    = (u16)(u >> 16);
  float r1  = v - __uint_as_float(u & 0xFFFF0000u);   // exact
  uint32 u2 = __float_as_uint(r1);
  u16 s2    = (u16)(u2 >> 16);
  float r2  = r1 - __uint_as_float(u2 & 0xFFFF0000u); // exact
  u16 s3    = (u16)(__float_as_uint(r2) >> 16);       // r2 fits bf16 exactly
  return {s1, s2, s3};
}

// ===========================================================================
// K1: xin = x @ W_in + b_in   (M=32768, N=1024, K=1024) in fp32-emulated
// bf16x3 MFMA (6 products). Tile 128x128, BK=32, 256 thr (4 waves), grid 2048.
// ===========================================================================
__global__ __launch_bounds__(256, 2) void gemm6(const float* __restrict__ x,
                                                const float* __restrict__ win,
                                                const float* __restrict__ bin,
                                                float* __restrict__ out) {
  __shared__ u16 As[3][128 * 40];  // [split][m][k], pad 40 -> 2-way banks (free)
  __shared__ u16 Bs[3][128 * 40];  // [split][n][k]
  const int bm = blockIdx.x >> 3, bn = blockIdx.x & 7;
  const int tid = threadIdx.x;
  const int w = tid >> 6, lane = tid & 63, quad = lane >> 4, li = lane & 15;
  const int row0 = bm * 128, col0 = bn * 128;

  f32x4 acc[2][8];
#pragma unroll
  for (int a = 0; a < 2; ++a)
#pragma unroll
    for (int b = 0; b < 8; ++b) acc[a][b] = (f32x4){0.f, 0.f, 0.f, 0.f};

  const int bc = tid & 127;       // B: this thread's local col
  const int bkh = tid >> 7;       // B: k-half (0/1) -> k = bkh*16 + kk

  for (int kb = 0; kb < 32; ++kb) {
    __syncthreads();
    // ---- stage A: 128m x 32k fp32 -> 3 split planes ----
#pragma unroll
    for (int i = 0; i < 4; ++i) {
      int idx = i * 256 + tid;                 // 0..1023 float4s
      int m = idx >> 3, kq = (idx & 7) * 4;
      float4 v = *(const float4*)&x[(size_t)(row0 + m) * 1024 + kb * 32 + kq];
      Split3 s0 = split3(v.x), s1 = split3(v.y), s2 = split3(v.z), s3 = split3(v.w);
      *(uint2*)&As[0][m * 40 + kq] = make_uint2((uint32)s0.a | ((uint32)s1.a << 16),
                                                (uint32)s2.a | ((uint32)s3.a << 16));
      *(uint2*)&As[1][m * 40 + kq] = make_uint2((uint32)s0.b | ((uint32)s1.b << 16),
                                                (uint32)s2.b | ((uint32)s3.b << 16));
      *(uint2*)&As[2][m * 40 + kq] = make_uint2((uint32)s0.c | ((uint32)s1.c << 16),
                                                (uint32)s2.c | ((uint32)s3.c << 16));
    }
    // ---- stage B: 32k x 128n, thread reads 16 k's of one col (coalesced) ----
    {
      u16 t1[16], t2[16], t3[16];
#pragma unroll
      for (int kk = 0; kk < 16; ++kk) {
        float v = win[(size_t)(kb * 32 + bkh * 16 + kk) * 1024 + col0 + bc];
        Split3 s = split3(v);
        t1[kk] = s.a; t2[kk] = s.b; t3[kk] = s.c;
      }
#pragma unroll
      for (int q = 0; q < 4; ++q) {
        int off = bc * 40 + bkh * 16 + q * 4;
        *(uint2*)&Bs[0][off] = make_uint2((uint32)t1[q*4] | ((uint32)t1[q*4+1] << 16),
                                          (uint32)t1[q*4+2] | ((uint32)t1[q*4+3] << 16));
        *(uint2*)&Bs[1][off] = make_uint2((uint32)t2[q*4] | ((uint32)t2[q*4+1] << 16),
                                          (uint32)t2[q*4+2] | ((uint32)t2[q*4+3] << 16));
        *(uint2*)&Bs[2][off] = make_uint2((uint32)t3[q*4] | ((uint32)t3[q*4+1] << 16),
                                          (uint32)t3[q*4+2] | ((uint32)t3[q*4+3] << 16));
      }
    }
    __syncthreads();
    // ---- compute: 2 m-tiles x 8 n-tiles x 6 split-products ----
    bf16x8 af[2][3];
#pragma unroll
    for (int mi = 0; mi < 2; ++mi)
#pragma unroll
      for (int s = 0; s < 3; ++s)
        af[mi][s] = *(const bf16x8*)&As[s][(w * 32 + mi * 16 + li) * 40 + quad * 8];
#pragma unroll
    for (int nf = 0; nf < 8; ++nf) {
      bf16x8 b1 = *(const bf16x8*)&Bs[0][(nf * 16 + li) * 40 + quad * 8];
      bf16x8 b2 = *(const bf16x8*)&Bs[1][(nf * 16 + li) * 40 + quad * 8];
      bf16x8 b3 = *(const bf16x8*)&Bs[2][(nf * 16 + li) * 40 + quad * 8];
#pragma unroll
      for (int mi = 0; mi < 2; ++mi) {
        f32x4 c = acc[mi][nf];
        c = __builtin_amdgcn_mfma_f32_16x16x32_bf16(af[mi][2], b1, c, 0, 0, 0); // a3*b1
        c = __builtin_amdgcn_mfma_f32_16x16x32_bf16(af[mi][1], b2, c, 0, 0, 0); // a2*b2
        c = __builtin_amdgcn_mfma_f32_16x16x32_bf16(af[mi][0], b3, c, 0, 0, 0); // a1*b3
        c = __builtin_amdgcn_mfma_f32_16x16x32_bf16(af[mi][1], b1, c, 0, 0, 0); // a2*b1
        c = __builtin_amdgcn_mfma_f32_16x16x32_bf16(af[mi][0], b2, c, 0, 0, 0); // a1*b2
        c = __builtin_amdgcn_mfma_f32_16x16x32_bf16(af[mi][0], b1, c, 0, 0, 0); // a1*b1
        acc[mi][nf] = c;
      }
    }
  }
  // ---- epilogue: + bias (no relu here; scan applies relu per step) ----
#pragma unroll
  for (int mi = 0; mi < 2; ++mi)
#pragma unroll
    for (int nf = 0; nf < 8; ++nf) {
      int gcol = col0 + nf * 16 + li;
      float bias = bin[gcol];
#pragma unroll
      for (int r = 0; r < 4; ++r) {
        int grow = row0 + w * 32 + mi * 16 + quad * 4 + r;
        out[(size_t)grow * 1024 + gcol] = acc[mi][nf][r] + bias;
      }
    }
}

// ===========================================================================
// K2: persistent recurrence, fp32-emulated via bf16x3. 64 WGs x 256 thr.
// 2 teams x 32 members; member owns 32 cols x 16 batches; waves k-split.
// W_hh slice pre-split into 48 B-frags (192 VGPRs). h exchanged pre-split as
// 3xbf16 via d_ws (ping-pong), staged to LDS in 2 k-passes (<64KB LDS).
// ===========================================================================
#define LROW 520         // 512 k-half + 8 pad (2-way banks only)
#define H16_PAR 98304    // u16 strides in hbuf: [par][team][split][b][k]
#define H16_TEAM 49152
#define H16_SPL 16384

__global__ __launch_bounds__(256, 1) void rnn_scan(const float* __restrict__ whh,
                                                   float* __restrict__ out,
                                                   void* ws) {
  uint32* ctr  = (uint32*)ws;                  // ctr[0], ctr[32]
  u16*    hbuf = (u16*)((char*)ws + 256);
  u64*    hb64 = (u64*)hbuf;
  uint32* hb32 = (uint32*)hbuf;

  const int wg = blockIdx.x, g = wg & 1, m = wg >> 1;
  const int tid = threadIdx.x;
  const int w = tid >> 6, lane = tid & 63, quad = lane >> 4, li = lane & 15;
  const int b0 = g * 16, f0 = m * 32;

  __shared__ u16  hT[48 * LROW];   // [split][b][k-half], 49.9 KB
  __shared__ float red[4][512];    // per-wave partials [b*32+col], 8 KB

  // ---- W_hh -> 48 register B-frags: wfr[p][kc][nt][s]; k = p*512+w*128+kc*32+quad*8+j
  bf16x8 wfr[2][4][2][3];
#pragma unroll
  for (int p = 0; p < 2; ++p)
#pragma unroll
    for (int kc = 0; kc < 4; ++kc)
#pragma unroll
      for (int nt = 0; nt < 2; ++nt) {
        ushort8 t1, t2, t3;
#pragma unroll
        for (int j = 0; j < 8; ++j) {
          float v = whh[(size_t)(p * 512 + w * 128 + kc * 32 + quad * 8 + j) * 1024
                        + f0 + nt * 16 + li];
          Split3 s = split3(v);
          t1[j] = s.a; t2[j] = s.b; t3[j] = s.c;
        }
        wfr[p][kc][nt][0] = __builtin_bit_cast(bf16x8, t1);
        wfr[p][kc][nt][1] = __builtin_bit_cast(bf16x8, t2);
        wfr[p][kc][nt][2] = __builtin_bit_cast(bf16x8, t3);
      }

  // epilogue ownership: thread -> (batch eb, col pair ecp)
  const int eb = tid >> 4, ecp = (tid & 15) * 2;

#pragma unroll 1
  for (int t = 0; t < 1024; ++t) {
    f32x4 acc0 = (f32x4){0.f, 0.f, 0.f, 0.f};
    f32x4 acc1 = (f32x4){0.f, 0.f, 0.f, 0.f};

    if (t > 0) {
      const uint32 target = 32u * (uint32)t;
      while (__hip_atomic_load(&ctr[g * 32], __ATOMIC_ACQUIRE,
                               __HIP_MEMORY_SCOPE_AGENT) < target)
        __builtin_amdgcn_s_sleep(2);

      const int par = (t - 1) & 1;
      const size_t base64 = (size_t)par * 24576 + (size_t)g * 12288;
#pragma unroll 1
      for (int p = 0; p < 2; ++p) {
        // stage 48KB (16b x 512k x 3 splits) of team-h into LDS
#pragma unroll 8
        for (int i = 0; i < 24; ++i) {
          int c = i * 256 + tid;            // 0..6143 u64 chunks
          int s = c >> 11, rem = c & 2047, b = rem >> 7, kq = rem & 127;
          u64 v = __hip_atomic_load(&hb64[base64 + s * 4096 + b * 256 + p * 128 + kq],
                                    __ATOMIC_RELAXED, __HIP_MEMORY_SCOPE_AGENT);
          *(uint2*)&hT[(s * 16 + b) * LROW + kq * 4] =
              make_uint2((uint32)v, (uint32)(v >> 32));
        }
        __syncthreads();
#pragma unroll
        for (int kc = 0; kc < 4; ++kc) {
          int ko = w * 128 + kc * 32 + quad * 8;
          bf16x8 a1 = *(const bf16x8*)&hT[(0 * 16 + li) * LROW + ko];
          bf16x8 a2 = *(const bf16x8*)&hT[(1 * 16 + li) * LROW + ko];
          bf16x8 a3 = *(const bf16x8*)&hT[(2 * 16 + li) * LROW + ko];
#pragma unroll
          for (int nt = 0; nt < 2; ++nt) {
            f32x4 c = nt ? acc1 : acc0;
            bf16x8 b1 = wfr[p][kc][nt][0], b2 = wfr[p][kc][nt][1], b3 = wfr[p][kc][nt][2];
            c = __builtin_amdgcn_mfma_f32_16x16x32_bf16(a3, b1, c, 0, 0, 0);
            c = __builtin_amdgcn_mfma_f32_16x16x32_bf16(a2, b2, c, 0, 0, 0);
            c = __builtin_amdgcn_mfma_f32_16x16x32_bf16(a1, b3, c, 0, 0, 0);
            c = __builtin_amdgcn_mfma_f32_16x16x32_bf16(a2, b1, c, 0, 0, 0);
            c = __builtin_amdgcn_mfma_f32_16x16x32_bf16(a1, b2, c, 0, 0, 0);
            c = __builtin_amdgcn_mfma_f32_16x16x32_bf16(a1, b1, c, 0, 0, 0);
            if (nt) acc1 = c; else acc0 = c;
          }
        }
        __syncthreads();  // hT reused by next pass / next step
      }
      // partials -> LDS (C layout: col=li, row=quad*4+r)
#pragma unroll
      for (int nt = 0; nt < 2; ++nt)
#pragma unroll
        for (int r = 0; r < 4; ++r) {
          red[w][(quad * 4 + r) * 32 + nt * 16 + li] = nt ? acc1[r] : acc0[r];
        }
      __syncthreads();
    }

    // ---- epilogue: v = relu(xin + sum4(partials)); in-place out; publish ----
    float sx = 0.f, sy = 0.f;
    if (t > 0) {
#pragma unroll
      for (int ww = 0; ww < 4; ++ww) {
        sx += red[ww][eb * 32 + ecp];
        sy += red[ww][eb * 32 + ecp + 1];
      }
    }
    size_t o = (size_t)(b0 + eb) * 1048576 + (size_t)t * 1024 + f0 + ecp;
    float2 xin = *(float2*)&out[o];
    float vx = fmaxf(xin.x + sx, 0.f);
    float vy = fmaxf(xin.y + sy, 0.f);
    *(float2*)&out[o] = make_float2(vx, vy);

    Split3 px = split3(vx), py = split3(vy);
    const uint32 pub = (uint32)((t & 1) * 49152 + g * 24576);  // u32 units
    const uint32 pe = (uint32)(eb * 512 + (f0 + ecp) / 2);
    __hip_atomic_store(&hb32[pub + 0 * 8192 + pe], (uint32)px.a | ((uint32)py.a << 16),
                       __ATOMIC_RELAXED, __HIP_MEMORY_SCOPE_AGENT);
    __hip_atomic_store(&hb32[pub + 1 * 8192 + pe], (uint32)px.b | ((uint32)py.b << 16),
                       __ATOMIC_RELAXED, __HIP_MEMORY_SCOPE_AGENT);
    __hip_atomic_store(&hb32[pub + 2 * 8192 + pe], (uint32)px.c | ((uint32)py.c << 16),
                       __ATOMIC_RELAXED, __HIP_MEMORY_SCOPE_AGENT);
    __syncthreads();  // all publishes done (drained to L2) before the release add
    if (tid == 0)
      __hip_atomic_fetch_add(&ctr[g * 32], 1u, __ATOMIC_RELEASE, __HIP_MEMORY_SCOPE_AGENT);
  }
}

// ---------------------------------------------------------------------------
// ws layout: [0,256) counters (memset 0); [256, 256+384K) h ping-pong triples.
// Total ws need: ~385 KB.
// ---------------------------------------------------------------------------
extern "C" void kernel_launch(void* const* d_in, const int* in_sizes, int n_in,
                              void* d_out, int out_size, void* d_ws, size_t ws_size,
                              hipStream_t stream) {
  const float* x   = (const float*)d_in[0];
  const float* win = (const float*)d_in[1];
  const float* bin = (const float*)d_in[2];
  const float* whh = (const float*)d_in[3];
  float* out = (float*)d_out;

  hipMemsetAsync(d_ws, 0, 256, stream);
  gemm6<<<2048, 256, 0, stream>>>(x, win, bin, out);

  static const float* whh_a; static float* out_a; static void* ws_a;
  whh_a = whh; out_a = out; ws_a = d_ws;
  void* args[3] = {(void*)&whh_a, (void*)&out_a, (void*)&ws_a};
  hipLaunchCooperativeKernel(reinterpret_cast<void*>(rnn_scan), dim3(64), dim3(256),
                             args, 0, stream);
}

// Round 6
// 22170.432 us; speedup vs baseline: 1.1718x; 1.1693x over previous
//
#include <hip/hip_runtime.h>

typedef unsigned int   uint32;
typedef unsigned short u16;
typedef unsigned long long u64;
typedef __bf16 bf16x8 __attribute__((ext_vector_type(8)));
typedef u16    ushort8 __attribute__((ext_vector_type(8)));
typedef float  f32x4  __attribute__((ext_vector_type(4)));

// ---------------------------------------------------------------------------
// Exact 3-way bf16 split (truncation): v == bf(a)+bf(b)+bf(c) EXACTLY for all
// normal fp32 (24 mantissa bits = 8+8+8; each subtraction is exact).
// ---------------------------------------------------------------------------
struct Split3 { u16 a, b, c; };
__device__ __forceinline__ Split3 split3(float v) {
  uint32 u  = __float_as_uint(v);
  u16 s1    = (u16)(u >> 16);
  float r1  = v - __uint_as_float(u & 0xFFFF0000u);   // exact
  uint32 u2 = __float_as_uint(r1);
  u16 s2    = (u16)(u2 >> 16);
  float r2  = r1 - __uint_as_float(u2 & 0xFFFF0000u); // exact
  u16 s3    = (u16)(__float_as_uint(r2) >> 16);       // r2 fits bf16 exactly
  return {s1, s2, s3};
}

// ===========================================================================
// K1: xin = x @ W_in + b_in   (M=32768, N=1024, K=1024) in fp32-emulated
// bf16x3 MFMA (6 products). Tile 128x128, BK=32, 256 thr (4 waves), grid 2048.
// ===========================================================================
__global__ __launch_bounds__(256, 2) void gemm6(const float* __restrict__ x,
                                                const float* __restrict__ win,
                                                const float* __restrict__ bin,
                                                float* __restrict__ out) {
  __shared__ u16 As[3][128 * 40];  // [split][m][k], pad 40 -> 2-way banks (free)
  __shared__ u16 Bs[3][128 * 40];  // [split][n][k]
  const int bm = blockIdx.x >> 3, bn = blockIdx.x & 7;
  const int tid = threadIdx.x;
  const int w = tid >> 6, lane = tid & 63, quad = lane >> 4, li = lane & 15;
  const int row0 = bm * 128, col0 = bn * 128;

  f32x4 acc[2][8];
#pragma unroll
  for (int a = 0; a < 2; ++a)
#pragma unroll
    for (int b = 0; b < 8; ++b) acc[a][b] = (f32x4){0.f, 0.f, 0.f, 0.f};

  const int bc = tid & 127;       // B: this thread's local col
  const int bkh = tid >> 7;       // B: k-half (0/1) -> k = bkh*16 + kk

  for (int kb = 0; kb < 32; ++kb) {
    __syncthreads();
    // ---- stage A: 128m x 32k fp32 -> 3 split planes ----
#pragma unroll
    for (int i = 0; i < 4; ++i) {
      int idx = i * 256 + tid;                 // 0..1023 float4s
      int m = idx >> 3, kq = (idx & 7) * 4;
      float4 v = *(const float4*)&x[(size_t)(row0 + m) * 1024 + kb * 32 + kq];
      Split3 s0 = split3(v.x), s1 = split3(v.y), s2 = split3(v.z), s3 = split3(v.w);
      *(uint2*)&As[0][m * 40 + kq] = make_uint2((uint32)s0.a | ((uint32)s1.a << 16),
                                                (uint32)s2.a | ((uint32)s3.a << 16));
      *(uint2*)&As[1][m * 40 + kq] = make_uint2((uint32)s0.b | ((uint32)s1.b << 16),
                                                (uint32)s2.b | ((uint32)s3.b << 16));
      *(uint2*)&As[2][m * 40 + kq] = make_uint2((uint32)s0.c | ((uint32)s1.c << 16),
                                                (uint32)s2.c | ((uint32)s3.c << 16));
    }
    // ---- stage B: 32k x 128n, thread reads 16 k's of one col (coalesced) ----
    {
      u16 t1[16], t2[16], t3[16];
#pragma unroll
      for (int kk = 0; kk < 16; ++kk) {
        float v = win[(size_t)(kb * 32 + bkh * 16 + kk) * 1024 + col0 + bc];
        Split3 s = split3(v);
        t1[kk] = s.a; t2[kk] = s.b; t3[kk] = s.c;
      }
#pragma unroll
      for (int q = 0; q < 4; ++q) {
        int off = bc * 40 + bkh * 16 + q * 4;
        *(uint2*)&Bs[0][off] = make_uint2((uint32)t1[q*4] | ((uint32)t1[q*4+1] << 16),
                                          (uint32)t1[q*4+2] | ((uint32)t1[q*4+3] << 16));
        *(uint2*)&Bs[1][off] = make_uint2((uint32)t2[q*4] | ((uint32)t2[q*4+1] << 16),
                                          (uint32)t2[q*4+2] | ((uint32)t2[q*4+3] << 16));
        *(uint2*)&Bs[2][off] = make_uint2((uint32)t3[q*4] | ((uint32)t3[q*4+1] << 16),
                                          (uint32)t3[q*4+2] | ((uint32)t3[q*4+3] << 16));
      }
    }
    __syncthreads();
    // ---- compute: 2 m-tiles x 8 n-tiles x 6 split-products ----
    bf16x8 af[2][3];
#pragma unroll
    for (int mi = 0; mi < 2; ++mi)
#pragma unroll
      for (int s = 0; s < 3; ++s)
        af[mi][s] = *(const bf16x8*)&As[s][(w * 32 + mi * 16 + li) * 40 + quad * 8];
#pragma unroll
    for (int nf = 0; nf < 8; ++nf) {
      bf16x8 b1 = *(const bf16x8*)&Bs[0][(nf * 16 + li) * 40 + quad * 8];
      bf16x8 b2 = *(const bf16x8*)&Bs[1][(nf * 16 + li) * 40 + quad * 8];
      bf16x8 b3 = *(const bf16x8*)&Bs[2][(nf * 16 + li) * 40 + quad * 8];
#pragma unroll
      for (int mi = 0; mi < 2; ++mi) {
        f32x4 c = acc[mi][nf];
        c = __builtin_amdgcn_mfma_f32_16x16x32_bf16(af[mi][2], b1, c, 0, 0, 0); // a3*b1
        c = __builtin_amdgcn_mfma_f32_16x16x32_bf16(af[mi][1], b2, c, 0, 0, 0); // a2*b2
        c = __builtin_amdgcn_mfma_f32_16x16x32_bf16(af[mi][0], b3, c, 0, 0, 0); // a1*b3
        c = __builtin_amdgcn_mfma_f32_16x16x32_bf16(af[mi][1], b1, c, 0, 0, 0); // a2*b1
        c = __builtin_amdgcn_mfma_f32_16x16x32_bf16(af[mi][0], b2, c, 0, 0, 0); // a1*b2
        c = __builtin_amdgcn_mfma_f32_16x16x32_bf16(af[mi][0], b1, c, 0, 0, 0); // a1*b1
        acc[mi][nf] = c;
      }
    }
  }
  // ---- epilogue: + bias (no relu here; scan applies relu per step) ----
#pragma unroll
  for (int mi = 0; mi < 2; ++mi)
#pragma unroll
    for (int nf = 0; nf < 8; ++nf) {
      int gcol = col0 + nf * 16 + li;
      float bias = bin[gcol];
#pragma unroll
      for (int r = 0; r < 4; ++r) {
        int grow = row0 + w * 32 + mi * 16 + quad * 4 + r;
        out[(size_t)grow * 1024 + gcol] = acc[mi][nf][r] + bias;
      }
    }
}

// ===========================================================================
// K2 v6: persistent recurrence. FROZEN CORE = v1: rolled p-loop
// (#pragma unroll 1), wfr runtime-indexed (scratch-resident — register
// promotion via unrolled/straight-line p MISCOMPILES deterministically:
// v2/v3/v4/v5 all failed absmax 5.5; v5 was the pragma alone). MFMA order,
// staging indices, epilogue, numerics: v1 verbatim.
//
// v6 changes (protocol/scheduling only):
//  - Flag-line sync: the per-team atomic COUNTER (32 serialized agent RMWs
//    per step on one line, hammered by 256 polling waves) is replaced by
//    32 per-WG flag words in one 128B line per team. Producer tid0 does a
//    release STORE of t+1 to its own word; only tid<32 poll (acquire, one
//    flag each), then __syncthreads joins the WG. Same happens-before
//    structure as v1 (data stores -> release -> acquire -> barrier -> loads).
//  - Staging i-loop fully unrolled (was unroll 8): all 24 u64 loads of a
//    pass issue in one flight (~1 LLC round-trip per pass instead of ~3).
// ===========================================================================
#define LROW 520         // 512 k-half + 8 pad (2-way banks only)

__global__ __launch_bounds__(256, 1) void rnn_scan(const float* __restrict__ whh,
                                                   float* __restrict__ out,
                                                   void* ws) {
  uint32* ctr  = (uint32*)ws;                  // flags: ctr[g*32 + m], 64 words
  u16*    hbuf = (u16*)((char*)ws + 256);
  u64*    hb64 = (u64*)hbuf;
  uint32* hb32 = (uint32*)hbuf;

  const int wg = blockIdx.x, g = wg & 1, m = wg >> 1;
  const int tid = threadIdx.x;
  const int w = tid >> 6, lane = tid & 63, quad = lane >> 4, li = lane & 15;
  const int b0 = g * 16, f0 = m * 32;

  __shared__ u16  hT[48 * LROW];   // [split][b][k-half], 49.9 KB
  __shared__ float red[4][512];    // per-wave partials [b*32+col], 8 KB

  // ---- W_hh -> 48 B-frags: wfr[p][kc][nt][s]; k = p*512+w*128+kc*32+quad*8+j
  bf16x8 wfr[2][4][2][3];
#pragma unroll
  for (int p = 0; p < 2; ++p)
#pragma unroll
    for (int kc = 0; kc < 4; ++kc)
#pragma unroll
      for (int nt = 0; nt < 2; ++nt) {
        ushort8 t1, t2, t3;
#pragma unroll
        for (int j = 0; j < 8; ++j) {
          float v = whh[(size_t)(p * 512 + w * 128 + kc * 32 + quad * 8 + j) * 1024
                        + f0 + nt * 16 + li];
          Split3 s = split3(v);
          t1[j] = s.a; t2[j] = s.b; t3[j] = s.c;
        }
        wfr[p][kc][nt][0] = __builtin_bit_cast(bf16x8, t1);
        wfr[p][kc][nt][1] = __builtin_bit_cast(bf16x8, t2);
        wfr[p][kc][nt][2] = __builtin_bit_cast(bf16x8, t3);
      }

  // epilogue ownership: thread -> (batch eb, col pair ecp)
  const int eb = tid >> 4, ecp = (tid & 15) * 2;

#pragma unroll 1
  for (int t = 0; t < 1024; ++t) {
    f32x4 acc0 = (f32x4){0.f, 0.f, 0.f, 0.f};
    f32x4 acc1 = (f32x4){0.f, 0.f, 0.f, 0.f};

    if (t > 0) {
      // ---- poll: tid<32 each own one producer flag; barrier joins the WG ----
      if (tid < 32) {
        const uint32 target = (uint32)t;
        while (__hip_atomic_load(&ctr[g * 32 + tid], __ATOMIC_ACQUIRE,
                                 __HIP_MEMORY_SCOPE_AGENT) < target)
          __builtin_amdgcn_s_sleep(2);
      }
      __syncthreads();

      const int par = (t - 1) & 1;
      const size_t base64 = (size_t)par * 24576 + (size_t)g * 12288;
#pragma unroll 1
      for (int p = 0; p < 2; ++p) {
        // stage 48KB (16b x 512k x 3 splits) of team-h into LDS; all 24
        // loads of the pass issue before the LDS writes (single flight)
#pragma unroll
        for (int i = 0; i < 24; ++i) {
          int c = i * 256 + tid;            // 0..6143 u64 chunks
          int s = c >> 11, rem = c & 2047, b = rem >> 7, kq = rem & 127;
          u64 v = __hip_atomic_load(&hb64[base64 + s * 4096 + b * 256 + p * 128 + kq],
                                    __ATOMIC_RELAXED, __HIP_MEMORY_SCOPE_AGENT);
          *(uint2*)&hT[(s * 16 + b) * LROW + kq * 4] =
              make_uint2((uint32)v, (uint32)(v >> 32));
        }
        __syncthreads();
#pragma unroll
        for (int kc = 0; kc < 4; ++kc) {
          int ko = w * 128 + kc * 32 + quad * 8;
          bf16x8 a1 = *(const bf16x8*)&hT[(0 * 16 + li) * LROW + ko];
          bf16x8 a2 = *(const bf16x8*)&hT[(1 * 16 + li) * LROW + ko];
          bf16x8 a3 = *(const bf16x8*)&hT[(2 * 16 + li) * LROW + ko];
#pragma unroll
          for (int nt = 0; nt < 2; ++nt) {
            f32x4 c = nt ? acc1 : acc0;
            bf16x8 b1 = wfr[p][kc][nt][0], b2 = wfr[p][kc][nt][1], b3 = wfr[p][kc][nt][2];
            c = __builtin_amdgcn_mfma_f32_16x16x32_bf16(a3, b1, c, 0, 0, 0);
            c = __builtin_amdgcn_mfma_f32_16x16x32_bf16(a2, b2, c, 0, 0, 0);
            c = __builtin_amdgcn_mfma_f32_16x16x32_bf16(a1, b3, c, 0, 0, 0);
            c = __builtin_amdgcn_mfma_f32_16x16x32_bf16(a2, b1, c, 0, 0, 0);
            c = __builtin_amdgcn_mfma_f32_16x16x32_bf16(a1, b2, c, 0, 0, 0);
            c = __builtin_amdgcn_mfma_f32_16x16x32_bf16(a1, b1, c, 0, 0, 0);
            if (nt) acc1 = c; else acc0 = c;
          }
        }
        __syncthreads();  // hT reused by next pass / next step
      }
      // partials -> LDS (C layout: col=li, row=quad*4+r)
#pragma unroll
      for (int nt = 0; nt < 2; ++nt)
#pragma unroll
        for (int r = 0; r < 4; ++r) {
          red[w][(quad * 4 + r) * 32 + nt * 16 + li] = nt ? acc1[r] : acc0[r];
        }
      __syncthreads();
    }

    // ---- epilogue: v = relu(xin + sum4(partials)); in-place out; publish ----
    float sx = 0.f, sy = 0.f;
    if (t > 0) {
#pragma unroll
      for (int ww = 0; ww < 4; ++ww) {
        sx += red[ww][eb * 32 + ecp];
        sy += red[ww][eb * 32 + ecp + 1];
      }
    }
    size_t o = (size_t)(b0 + eb) * 1048576 + (size_t)t * 1024 + f0 + ecp;
    float2 xin = *(float2*)&out[o];
    float vx = fmaxf(xin.x + sx, 0.f);
    float vy = fmaxf(xin.y + sy, 0.f);
    *(float2*)&out[o] = make_float2(vx, vy);

    Split3 px = split3(vx), py = split3(vy);
    const uint32 pub = (uint32)((t & 1) * 49152 + g * 24576);  // u32 units
    const uint32 pe = (uint32)(eb * 512 + (f0 + ecp) / 2);
    __hip_atomic_store(&hb32[pub + 0 * 8192 + pe], (uint32)px.a | ((uint32)py.a << 16),
                       __ATOMIC_RELAXED, __HIP_MEMORY_SCOPE_AGENT);
    __hip_atomic_store(&hb32[pub + 1 * 8192 + pe], (uint32)px.b | ((uint32)py.b << 16),
                       __ATOMIC_RELAXED, __HIP_MEMORY_SCOPE_AGENT);
    __hip_atomic_store(&hb32[pub + 2 * 8192 + pe], (uint32)px.c | ((uint32)py.c << 16),
                       __ATOMIC_RELAXED, __HIP_MEMORY_SCOPE_AGENT);
    __syncthreads();  // all publishes drained before the release flag store
    if (tid == 0)
      __hip_atomic_store(&ctr[g * 32 + m], (uint32)(t + 1), __ATOMIC_RELEASE,
                         __HIP_MEMORY_SCOPE_AGENT);
  }
}

// ---------------------------------------------------------------------------
// ws layout: [0,256) flags (memset 0); [256, 256+384K) h ping-pong triples.
// Total ws need: ~385 KB.
// ---------------------------------------------------------------------------
extern "C" void kernel_launch(void* const* d_in, const int* in_sizes, int n_in,
                              void* d_out, int out_size, void* d_ws, size_t ws_size,
                              hipStream_t stream) {
  const float* x   = (const float*)d_in[0];
  const float* win = (const float*)d_in[1];
  const float* bin = (const float*)d_in[2];
  const float* whh = (const float*)d_in[3];
  float* out = (float*)d_out;

  hipMemsetAsync(d_ws, 0, 256, stream);
  gemm6<<<2048, 256, 0, stream>>>(x, win, bin, out);

  static const float* whh_a; static float* out_a; static void* ws_a;
  whh_a = whh; out_a = out; ws_a = d_ws;
  void* args[3] = {(void*)&whh_a, (void*)&out_a, (void*)&ws_a};
  hipLaunchCooperativeKernel(reinterpret_cast<void*>(rnn_scan), dim3(64), dim3(256),
                             args, 0, stream);
}

// Round 7
// 21285.484 us; speedup vs baseline: 1.2206x; 1.0416x over previous
//
#include <hip/hip_runtime.h>

typedef unsigned int   uint32;
typedef unsigned short u16;
typedef unsigned long long u64;
typedef __bf16 bf16x8 __attribute__((ext_vector_type(8)));
typedef u16    ushort8 __attribute__((ext_vector_type(8)));
typedef float  f32x4  __attribute__((ext_vector_type(4)));

// ---------------------------------------------------------------------------
// Exact 3-way bf16 split (truncation): v == bf(a)+bf(b)+bf(c) EXACTLY for all
// normal fp32 (24 mantissa bits = 8+8+8; each subtraction is exact).
// ---------------------------------------------------------------------------
struct Split3 { u16 a, b, c; };
__device__ __forceinline__ Split3 split3(float v) {
  uint32 u  = __float_as_uint(v);
  u16 s1    = (u16)(u >> 16);
  float r1  = v - __uint_as_float(u & 0xFFFF0000u);   // exact
  uint32 u2 = __float_as_uint(r1);
  u16 s2    = (u16)(u2 >> 16);
  float r2  = r1 - __uint_as_float(u2 & 0xFFFF0000u); // exact
  u16 s3    = (u16)(__float_as_uint(r2) >> 16);       // r2 fits bf16 exactly
  return {s1, s2, s3};
}

// ===========================================================================
// K1: xin = x @ W_in + b_in   (M=32768, N=1024, K=1024) in fp32-emulated
// bf16x3 MFMA (6 products). Tile 128x128, BK=32, 256 thr (4 waves), grid 2048.
// ===========================================================================
__global__ __launch_bounds__(256, 2) void gemm6(const float* __restrict__ x,
                                                const float* __restrict__ win,
                                                const float* __restrict__ bin,
                                                float* __restrict__ out) {
  __shared__ u16 As[3][128 * 40];  // [split][m][k], pad 40 -> 2-way banks (free)
  __shared__ u16 Bs[3][128 * 40];  // [split][n][k]
  const int bm = blockIdx.x >> 3, bn = blockIdx.x & 7;
  const int tid = threadIdx.x;
  const int w = tid >> 6, lane = tid & 63, quad = lane >> 4, li = lane & 15;
  const int row0 = bm * 128, col0 = bn * 128;

  f32x4 acc[2][8];
#pragma unroll
  for (int a = 0; a < 2; ++a)
#pragma unroll
    for (int b = 0; b < 8; ++b) acc[a][b] = (f32x4){0.f, 0.f, 0.f, 0.f};

  const int bc = tid & 127;       // B: this thread's local col
  const int bkh = tid >> 7;       // B: k-half (0/1) -> k = bkh*16 + kk

  for (int kb = 0; kb < 32; ++kb) {
    __syncthreads();
    // ---- stage A: 128m x 32k fp32 -> 3 split planes ----
#pragma unroll
    for (int i = 0; i < 4; ++i) {
      int idx = i * 256 + tid;                 // 0..1023 float4s
      int m = idx >> 3, kq = (idx & 7) * 4;
      float4 v = *(const float4*)&x[(size_t)(row0 + m) * 1024 + kb * 32 + kq];
      Split3 s0 = split3(v.x), s1 = split3(v.y), s2 = split3(v.z), s3 = split3(v.w);
      *(uint2*)&As[0][m * 40 + kq] = make_uint2((uint32)s0.a | ((uint32)s1.a << 16),
                                                (uint32)s2.a | ((uint32)s3.a << 16));
      *(uint2*)&As[1][m * 40 + kq] = make_uint2((uint32)s0.b | ((uint32)s1.b << 16),
                                                (uint32)s2.b | ((uint32)s3.b << 16));
      *(uint2*)&As[2][m * 40 + kq] = make_uint2((uint32)s0.c | ((uint32)s1.c << 16),
                                                (uint32)s2.c | ((uint32)s3.c << 16));
    }
    // ---- stage B: 32k x 128n, thread reads 16 k's of one col (coalesced) ----
    {
      u16 t1[16], t2[16], t3[16];
#pragma unroll
      for (int kk = 0; kk < 16; ++kk) {
        float v = win[(size_t)(kb * 32 + bkh * 16 + kk) * 1024 + col0 + bc];
        Split3 s = split3(v);
        t1[kk] = s.a; t2[kk] = s.b; t3[kk] = s.c;
      }
#pragma unroll
      for (int q = 0; q < 4; ++q) {
        int off = bc * 40 + bkh * 16 + q * 4;
        *(uint2*)&Bs[0][off] = make_uint2((uint32)t1[q*4] | ((uint32)t1[q*4+1] << 16),
                                          (uint32)t1[q*4+2] | ((uint32)t1[q*4+3] << 16));
        *(uint2*)&Bs[1][off] = make_uint2((uint32)t2[q*4] | ((uint32)t2[q*4+1] << 16),
                                          (uint32)t2[q*4+2] | ((uint32)t2[q*4+3] << 16));
        *(uint2*)&Bs[2][off] = make_uint2((uint32)t3[q*4] | ((uint32)t3[q*4+1] << 16),
                                          (uint32)t3[q*4+2] | ((uint32)t3[q*4+3] << 16));
      }
    }
    __syncthreads();
    // ---- compute: 2 m-tiles x 8 n-tiles x 6 split-products ----
    bf16x8 af[2][3];
#pragma unroll
    for (int mi = 0; mi < 2; ++mi)
#pragma unroll
      for (int s = 0; s < 3; ++s)
        af[mi][s] = *(const bf16x8*)&As[s][(w * 32 + mi * 16 + li) * 40 + quad * 8];
#pragma unroll
    for (int nf = 0; nf < 8; ++nf) {
      bf16x8 b1 = *(const bf16x8*)&Bs[0][(nf * 16 + li) * 40 + quad * 8];
      bf16x8 b2 = *(const bf16x8*)&Bs[1][(nf * 16 + li) * 40 + quad * 8];
      bf16x8 b3 = *(const bf16x8*)&Bs[2][(nf * 16 + li) * 40 + quad * 8];
#pragma unroll
      for (int mi = 0; mi < 2; ++mi) {
        f32x4 c = acc[mi][nf];
        c = __builtin_amdgcn_mfma_f32_16x16x32_bf16(af[mi][2], b1, c, 0, 0, 0); // a3*b1
        c = __builtin_amdgcn_mfma_f32_16x16x32_bf16(af[mi][1], b2, c, 0, 0, 0); // a2*b2
        c = __builtin_amdgcn_mfma_f32_16x16x32_bf16(af[mi][0], b3, c, 0, 0, 0); // a1*b3
        c = __builtin_amdgcn_mfma_f32_16x16x32_bf16(af[mi][1], b1, c, 0, 0, 0); // a2*b1
        c = __builtin_amdgcn_mfma_f32_16x16x32_bf16(af[mi][0], b2, c, 0, 0, 0); // a1*b2
        c = __builtin_amdgcn_mfma_f32_16x16x32_bf16(af[mi][0], b1, c, 0, 0, 0); // a1*b1
        acc[mi][nf] = c;
      }
    }
  }
  // ---- epilogue: + bias (no relu here; scan applies relu per step) ----
#pragma unroll
  for (int mi = 0; mi < 2; ++mi)
#pragma unroll
    for (int nf = 0; nf < 8; ++nf) {
      int gcol = col0 + nf * 16 + li;
      float bias = bin[gcol];
#pragma unroll
      for (int r = 0; r < 4; ++r) {
        int grow = row0 + w * 32 + mi * 16 + quad * 4 + r;
        out[(size_t)grow * 1024 + gcol] = acc[mi][nf][r] + bias;
      }
    }
}

// ===========================================================================
// K2 v7: persistent recurrence, 32 WGs x 512 thr (was 64 x 256).
// 2 teams x 16 members; member owns 64 cols x 16 batches; 8 waves k-split
// (wave w covers k = p*512 + w*64 + kc*32 within pass p).
//
// FROZEN CORE (do not touch): rolled p-loop (#pragma unroll 1), wfr
// runtime-p-indexed (scratch-resident — register promotion via unrolled p
// MISCOMPILES deterministically: v2-v5 all absmax 5.5; v5 isolated the
// pragma). Acquire poll per iteration. v6 flag-store protocol (proven).
// MFMA order / split3 numerics identical.
//
// v7 change (protocol scale only): halve WG count, double WG width.
//  - producer fan-in per team 32 -> 16 flags; polling waves 64 -> 32;
//    per-step LLC staging traffic 6 MB -> 3 MB; per-thread work unchanged.
//  Tests the theory that the ~17 us/step unexplained time is max-of-N
//  producer arrival + poll/invalidate fabric contention.
// ===========================================================================
#define LROW 520         // 512 k-half + 8 pad (2-way banks only)

__global__ __launch_bounds__(512, 1) void rnn_scan(const float* __restrict__ whh,
                                                   float* __restrict__ out,
                                                   void* ws) {
  uint32* ctr  = (uint32*)ws;                  // flags: ctr[g*32 + m], m<16
  u16*    hbuf = (u16*)((char*)ws + 256);
  u64*    hb64 = (u64*)hbuf;
  uint32* hb32 = (uint32*)hbuf;

  const int wg = blockIdx.x, g = wg & 1, m = wg >> 1;   // m in 0..15
  const int tid = threadIdx.x;
  const int w = tid >> 6, lane = tid & 63, quad = lane >> 4, li = lane & 15;
  const int b0 = g * 16, f0 = m * 64;

  __shared__ u16  hT[48 * LROW];   // [split][b][k-half], 49.9 KB
  __shared__ float red[8][1024];   // per-wave partials [b*64+col], 32 KB

  // ---- W_hh -> 48 B-frags: wfr[p][kc][nt][s]; k = p*512+w*64+kc*32+quad*8+j
  bf16x8 wfr[2][2][4][3];
#pragma unroll
  for (int p = 0; p < 2; ++p)
#pragma unroll
    for (int kc = 0; kc < 2; ++kc)
#pragma unroll
      for (int nt = 0; nt < 4; ++nt) {
        ushort8 t1, t2, t3;
#pragma unroll
        for (int j = 0; j < 8; ++j) {
          float v = whh[(size_t)(p * 512 + w * 64 + kc * 32 + quad * 8 + j) * 1024
                        + f0 + nt * 16 + li];
          Split3 s = split3(v);
          t1[j] = s.a; t2[j] = s.b; t3[j] = s.c;
        }
        wfr[p][kc][nt][0] = __builtin_bit_cast(bf16x8, t1);
        wfr[p][kc][nt][1] = __builtin_bit_cast(bf16x8, t2);
        wfr[p][kc][nt][2] = __builtin_bit_cast(bf16x8, t3);
      }

  // epilogue ownership: thread -> (batch eb, col pair ecp), 512 thr cover 16x64
  const int eb = tid >> 5, ecp = (tid & 31) * 2;

#pragma unroll 1
  for (int t = 0; t < 1024; ++t) {
    f32x4 acc[4];
#pragma unroll
    for (int nt = 0; nt < 4; ++nt) acc[nt] = (f32x4){0.f, 0.f, 0.f, 0.f};

    if (t > 0) {
      // ---- poll: tid<16 each own one producer flag; barrier joins the WG ----
      if (tid < 16) {
        const uint32 target = (uint32)t;
        while (__hip_atomic_load(&ctr[g * 32 + tid], __ATOMIC_ACQUIRE,
                                 __HIP_MEMORY_SCOPE_AGENT) < target)
          __builtin_amdgcn_s_sleep(2);
      }
      __syncthreads();

      const int par = (t - 1) & 1;
      const size_t base64 = (size_t)par * 24576 + (size_t)g * 12288;
#pragma unroll 1
      for (int p = 0; p < 2; ++p) {
        // stage 48KB (16b x 512k x 3 splits) of team-h into LDS, single flight
#pragma unroll
        for (int i = 0; i < 12; ++i) {
          int c = i * 512 + tid;            // 0..6143 u64 chunks
          int s = c >> 11, rem = c & 2047, b = rem >> 7, kq = rem & 127;
          u64 v = __hip_atomic_load(&hb64[base64 + s * 4096 + b * 256 + p * 128 + kq],
                                    __ATOMIC_RELAXED, __HIP_MEMORY_SCOPE_AGENT);
          *(uint2*)&hT[(s * 16 + b) * LROW + kq * 4] =
              make_uint2((uint32)v, (uint32)(v >> 32));
        }
        __syncthreads();
#pragma unroll
        for (int kc = 0; kc < 2; ++kc) {
          int ko = w * 64 + kc * 32 + quad * 8;
          bf16x8 a1 = *(const bf16x8*)&hT[(0 * 16 + li) * LROW + ko];
          bf16x8 a2 = *(const bf16x8*)&hT[(1 * 16 + li) * LROW + ko];
          bf16x8 a3 = *(const bf16x8*)&hT[(2 * 16 + li) * LROW + ko];
#pragma unroll
          for (int nt = 0; nt < 4; ++nt) {
            f32x4 c = acc[nt];
            bf16x8 b1 = wfr[p][kc][nt][0], b2 = wfr[p][kc][nt][1], b3 = wfr[p][kc][nt][2];
            c = __builtin_amdgcn_mfma_f32_16x16x32_bf16(a3, b1, c, 0, 0, 0);
            c = __builtin_amdgcn_mfma_f32_16x16x32_bf16(a2, b2, c, 0, 0, 0);
            c = __builtin_amdgcn_mfma_f32_16x16x32_bf16(a1, b3, c, 0, 0, 0);
            c = __builtin_amdgcn_mfma_f32_16x16x32_bf16(a2, b1, c, 0, 0, 0);
            c = __builtin_amdgcn_mfma_f32_16x16x32_bf16(a1, b2, c, 0, 0, 0);
            c = __builtin_amdgcn_mfma_f32_16x16x32_bf16(a1, b1, c, 0, 0, 0);
            acc[nt] = c;
          }
        }
        __syncthreads();  // hT reused by next pass / next step
      }
      // partials -> LDS (C layout: col=li, row=quad*4+r)
#pragma unroll
      for (int nt = 0; nt < 4; ++nt)
#pragma unroll
        for (int r = 0; r < 4; ++r) {
          red[w][(quad * 4 + r) * 64 + nt * 16 + li] = acc[nt][r];
        }
      __syncthreads();
    }

    // ---- epilogue: v = relu(xin + sum8(partials)); in-place out; publish ----
    float sx = 0.f, sy = 0.f;
    if (t > 0) {
#pragma unroll
      for (int ww = 0; ww < 8; ++ww) {
        sx += red[ww][eb * 64 + ecp];
        sy += red[ww][eb * 64 + ecp + 1];
      }
    }
    size_t o = (size_t)(b0 + eb) * 1048576 + (size_t)t * 1024 + f0 + ecp;
    float2 xin = *(float2*)&out[o];
    float vx = fmaxf(xin.x + sx, 0.f);
    float vy = fmaxf(xin.y + sy, 0.f);
    *(float2*)&out[o] = make_float2(vx, vy);

    Split3 px = split3(vx), py = split3(vy);
    const uint32 pub = (uint32)((t & 1) * 49152 + g * 24576);  // u32 units
    const uint32 pe = (uint32)(eb * 512 + (f0 + ecp) / 2);
    __hip_atomic_store(&hb32[pub + 0 * 8192 + pe], (uint32)px.a | ((uint32)py.a << 16),
                       __ATOMIC_RELAXED, __HIP_MEMORY_SCOPE_AGENT);
    __hip_atomic_store(&hb32[pub + 1 * 8192 + pe], (uint32)px.b | ((uint32)py.b << 16),
                       __ATOMIC_RELAXED, __HIP_MEMORY_SCOPE_AGENT);
    __hip_atomic_store(&hb32[pub + 2 * 8192 + pe], (uint32)px.c | ((uint32)py.c << 16),
                       __ATOMIC_RELAXED, __HIP_MEMORY_SCOPE_AGENT);
    __syncthreads();  // all publishes drained before the release flag store
    if (tid == 0)
      __hip_atomic_store(&ctr[g * 32 + m], (uint32)(t + 1), __ATOMIC_RELEASE,
                         __HIP_MEMORY_SCOPE_AGENT);
  }
}

// ---------------------------------------------------------------------------
// ws layout: [0,256) flags (memset 0); [256, 256+384K) h ping-pong triples.
// Total ws need: ~385 KB.
// ---------------------------------------------------------------------------
extern "C" void kernel_launch(void* const* d_in, const int* in_sizes, int n_in,
                              void* d_out, int out_size, void* d_ws, size_t ws_size,
                              hipStream_t stream) {
  const float* x   = (const float*)d_in[0];
  const float* win = (const float*)d_in[1];
  const float* bin = (const float*)d_in[2];
  const float* whh = (const float*)d_in[3];
  float* out = (float*)d_out;

  hipMemsetAsync(d_ws, 0, 256, stream);
  gemm6<<<2048, 256, 0, stream>>>(x, win, bin, out);

  static const float* whh_a; static float* out_a; static void* ws_a;
  whh_a = whh; out_a = out; ws_a = d_ws;
  void* args[3] = {(void*)&whh_a, (void*)&out_a, (void*)&ws_a};
  hipLaunchCooperativeKernel(reinterpret_cast<void*>(rnn_scan), dim3(32), dim3(512),
                             args, 0, stream);
}